// Round 17
// baseline (280.562 us; speedup 1.0000x reference)
//
#include <hip/hip_runtime.h>

#define TT 65
#define NSTEP 64

typedef __attribute__((ext_vector_type(8))) short bf16x8;
typedef __attribute__((ext_vector_type(4))) float f32x4;
typedef __attribute__((ext_vector_type(4))) unsigned int u32x4;

#define MFMA32(A,B,C) __builtin_amdgcn_mfma_f32_16x16x32_bf16((A),(B),(C),0,0,0)

#if __has_builtin(__builtin_amdgcn_exp2f)
#define EXP2F(x) __builtin_amdgcn_exp2f(x)
#else
#define EXP2F(x) __expf(0.6931471805599453f * (x))
#endif

__device__ constexpr float ATc[6][5] = {
    {0.f, 0.f, 0.f, 0.f, 0.f},
    {0.2f, 0.f, 0.f, 0.f, 0.f},
    {3.f/40.f, 9.f/40.f, 0.f, 0.f, 0.f},
    {44.f/45.f, -56.f/15.f, 32.f/9.f, 0.f, 0.f},
    {19372.f/6561.f, -25360.f/2187.f, 64448.f/6561.f, -212.f/729.f, 0.f},
    {9017.f/3168.f, -355.f/33.f, 46732.f/5247.f, 49.f/176.f, -5103.f/18656.f}
};
__device__ constexpr float BTc[6] = {35.f/384.f, 0.f, 500.f/1113.f, 125.f/192.f,
                                     -2187.f/6784.f, 11.f/84.f};

__device__ __forceinline__ float tanh_fast(float x) {
    float e = EXP2F(x * 2.8853900817779268f);
    return fmaf(-2.0f, __builtin_amdgcn_rcpf(e + 1.0f), 1.0f);
}

// weights-init pack (round-half-up via perm)
__device__ __forceinline__ unsigned int permhi(unsigned int b, unsigned int a) {
    return __builtin_amdgcn_perm(b, a, 0x07060302u);
}
__device__ __forceinline__ unsigned int packpair_init(float a, float b) {
    return permhi(__float_as_uint(b) + 0x8000u, __float_as_uint(a) + 0x8000u);
}
__device__ __forceinline__ bf16x8 pack8(const float* v) {
    u32x4 H = {packpair_init(v[0], v[1]), packpair_init(v[2], v[3]),
               packpair_init(v[4], v[5]), packpair_init(v[6], v[7])};
    return __builtin_bit_cast(bf16x8, H);
}

// hot-path pack via HW v_cvt_pk_bf16_f32 (R16-proven)
__device__ __forceinline__ unsigned int cvtpk(float a, float b) {
    unsigned int r;
    asm("v_cvt_pk_bf16_f32 %0, %1, %2" : "=v"(r) : "v"(a), "v"(b));
    return r;
}
__device__ __forceinline__ bf16x8 packz(f32x4 a, f32x4 b) {
    u32x4 H = {cvtpk(a[0], a[1]), cvtpk(a[2], a[3]),
               cvtpk(b[0], b[1]), cvtpk(b[2], b[3])};
    return __builtin_bit_cast(bf16x8, H);
}

__device__ __forceinline__ f32x4 fma4s(float c, f32x4 a, f32x4 b) {  // b + c*a
    f32x4 r;
    #pragma unroll
    for (int i = 0; i < 4; ++i) r[i] = fmaf(c, a[i], b[i]);
    return r;
}

// R17: ONE WAVE owns 16 rows end-to-end. Zero __syncthreads, zero LDS arrays.
// Lane (q = l>>4, r = l&15) holds state in MFMA D-layout: y[d][r] for
// d in {4q..4q+3} (tile 0) and {16+4q..16+4q+3} (tile 1).
// Per stage: B1 = yt B-fragment gathered IN-WAVE via 8 ds_bpermute + 4 cndmask
// (word j of B1 = packed yt pair from lane 32*(q&1) + 16*(j>=2) + r, regs
// P0/P1 for q<2, P2/P3 for q>=2 — mapping verified analytically);
// m1 = 8 MFMA32 (tiles independent); tanh x32; Zf[kf] = packz(z[2kf],z[2kf+1])
// feeds m2's K=128 via the sigma K-permutation (R12-proven); m2 = 2 d-tiles x
// 4 K-fragments (2+2 accumulator chains); k stays in registers; Butcher
// update fully local. Grid 512 x 64 thr = 2 independent waves/CU.
__global__ __launch_bounds__(64, 1)
void NeuralODE_dopri5_r17(const float* __restrict__ x, const float* __restrict__ tptr,
                          const float* __restrict__ W1, const float* __restrict__ b1,
                          const float* __restrict__ W2, const float* __restrict__ b2,
                          float* __restrict__ out)
{
    const int l = threadIdx.x;
    const int r = l & 15;
    const int q = l >> 4;
    const int row = blockIdx.x * 16 + r;

    // ---- weights: single-plane bf16 fragments (R15-proven numerics) ----
    bf16x8 W1f[8];
    f32x4 b1f[8];
    #pragma unroll
    for (int m = 0; m < 8; ++m) {
        float v[8];
        *(f32x4*)&v[0] = *(const f32x4*)&W1[(16*m + r) * 32 + 8*q];
        *(f32x4*)&v[4] = *(const f32x4*)&W1[(16*m + r) * 32 + 8*q + 4];
        W1f[m] = pack8(v);
        b1f[m] = *(const f32x4*)&b1[16*m + 4*q];
    }
    // W2 A-fragments, sigma K-permutation per 32-slice:
    //   A[r][8q+j] = W2[16dt + r][32kf + (j<4 ? 4q+j : 16 + 4q + j-4)]
    bf16x8 W2f[2][4];
    f32x4 b2f[2];
    #pragma unroll
    for (int dt = 0; dt < 2; ++dt) {
        b2f[dt] = *(const f32x4*)&b2[16*dt + 4*q];
        #pragma unroll
        for (int kf = 0; kf < 4; ++kf) {
            float v[8];
            *(f32x4*)&v[0] = *(const f32x4*)&W2[(16*dt + r) * 128 + 32*kf + 4*q];
            *(f32x4*)&v[4] = *(const f32x4*)&W2[(16*dt + r) * 128 + 32*kf + 16 + 4*q];
            W2f[dt][kf] = pack8(v);
        }
    }

    // ---- B1-gather lane addresses (bytes = 4 * src_lane) ----
    const int a01 = 4 * ((q & 1) * 32 + r);        // B1 words 0,1 source lane
    const int a23 = a01 + 64;                      // words 2,3: +16 lanes
    const bool hiq = (q >= 2);                     // select P2/P3 planes

    const float h_all = tptr[l + 1] - tptr[l];     // t row 0 uniform

    // ---- state init (D-layout, fully lane-local) ----
    f32x4 y0v = *(const f32x4*)&x[(size_t)row * (TT*32) + 4*q];
    f32x4 y1v = *(const f32x4*)&x[(size_t)row * (TT*32) + 16 + 4*q];
    *(f32x4*)&out[(size_t)row * (TT*32) + 4*q]      = y0v;
    *(f32x4*)&out[(size_t)row * (TT*32) + 16 + 4*q] = y1v;

    unsigned int P0  = cvtpk(y0v[0], y0v[1]);
    unsigned int P1  = cvtpk(y0v[2], y0v[3]);
    unsigned int P2c = cvtpk(y1v[0], y1v[1]);
    unsigned int P3  = cvtpk(y1v[2], y1v[3]);

    f32x4 kk0[5], kk1[5];
    const f32x4 zero = {0.f, 0.f, 0.f, 0.f};

    #pragma unroll 1
    for (int step = 0; step < NSTEP; ++step) {
        const float h = __shfl(h_all, step);
        f32x4 ba0 = zero, ba1 = zero;

        #pragma unroll
        for (int s = 0; s < 6; ++s) {
            // ---- B1 assembly: in-wave gather of packed yt pairs ----
            int w0a = __builtin_amdgcn_ds_bpermute(a01, (int)P0);
            int w0b = __builtin_amdgcn_ds_bpermute(a01, (int)P2c);
            int w1a = __builtin_amdgcn_ds_bpermute(a01, (int)P1);
            int w1b = __builtin_amdgcn_ds_bpermute(a01, (int)P3);
            int w2a = __builtin_amdgcn_ds_bpermute(a23, (int)P0);
            int w2b = __builtin_amdgcn_ds_bpermute(a23, (int)P2c);
            int w3a = __builtin_amdgcn_ds_bpermute(a23, (int)P1);
            int w3b = __builtin_amdgcn_ds_bpermute(a23, (int)P3);
            u32x4 Bw = { (unsigned int)(hiq ? w0b : w0a),
                         (unsigned int)(hiq ? w1b : w1a),
                         (unsigned int)(hiq ? w2b : w2a),
                         (unsigned int)(hiq ? w3b : w3a) };
            bf16x8 B1 = __builtin_bit_cast(bf16x8, Bw);

            // ---- m1: 8 independent MFMA32 + tanh x32 ----
            f32x4 z0 = MFMA32(W1f[0], B1, b1f[0]);
            f32x4 z1 = MFMA32(W1f[1], B1, b1f[1]);
            f32x4 z2 = MFMA32(W1f[2], B1, b1f[2]);
            f32x4 z3 = MFMA32(W1f[3], B1, b1f[3]);
            f32x4 z4 = MFMA32(W1f[4], B1, b1f[4]);
            f32x4 z5 = MFMA32(W1f[5], B1, b1f[5]);
            f32x4 z6 = MFMA32(W1f[6], B1, b1f[6]);
            f32x4 z7 = MFMA32(W1f[7], B1, b1f[7]);
            #pragma unroll
            for (int e = 0; e < 4; ++e) {
                z0[e] = tanh_fast(z0[e]); z1[e] = tanh_fast(z1[e]);
                z2[e] = tanh_fast(z2[e]); z3[e] = tanh_fast(z3[e]);
                z4[e] = tanh_fast(z4[e]); z5[e] = tanh_fast(z5[e]);
                z6[e] = tanh_fast(z6[e]); z7[e] = tanh_fast(z7[e]);
            }

            // ---- z -> 4 B-fragments (sigma concat, in-register) ----
            bf16x8 Zf0 = packz(z0, z1);
            bf16x8 Zf1 = packz(z2, z3);
            bf16x8 Zf2 = packz(z4, z5);
            bf16x8 Zf3 = packz(z6, z7);

            // ---- m2: K=128, 2 d-tiles x (2+2 accumulator chains) ----
            f32x4 k0, k1;
            {
                f32x4 pa = MFMA32(W2f[0][0], Zf0, b2f[0]);
                pa       = MFMA32(W2f[0][1], Zf1, pa);
                f32x4 pb = MFMA32(W2f[0][2], Zf2, zero);
                pb       = MFMA32(W2f[0][3], Zf3, pb);
                #pragma unroll
                for (int e = 0; e < 4; ++e) k0[e] = pa[e] + pb[e];
            }
            {
                f32x4 pa = MFMA32(W2f[1][0], Zf0, b2f[1]);
                pa       = MFMA32(W2f[1][1], Zf1, pa);
                f32x4 pb = MFMA32(W2f[1][2], Zf2, zero);
                pb       = MFMA32(W2f[1][3], Zf3, pb);
                #pragma unroll
                for (int e = 0; e < 4; ++e) k1[e] = pa[e] + pb[e];
            }

            // ---- Butcher update: fully lane-local ----
            ba0 = fma4s(BTc[s], k0, ba0);
            ba1 = fma4s(BTc[s], k1, ba1);

            f32x4 yt0, yt1;
            if (s < 5) {
                kk0[s] = k0; kk1[s] = k1;
                f32x4 ax = zero, ay = zero;
                #pragma unroll
                for (int j = 0; j < 5; ++j)
                    if (j <= s) { ax = fma4s(ATc[s+1][j], kk0[j], ax);
                                  ay = fma4s(ATc[s+1][j], kk1[j], ay); }
                yt0 = fma4s(h, ax, y0v);
                yt1 = fma4s(h, ay, y1v);
            } else {
                y0v = fma4s(h, ba0, y0v);
                y1v = fma4s(h, ba1, y1v);
                yt0 = y0v; yt1 = y1v;
                size_t o = (size_t)row * (TT*32) + (size_t)(step + 1) * 32;
                *(f32x4*)&out[o + 4*q]      = y0v;
                *(f32x4*)&out[o + 16 + 4*q] = y1v;
            }
            P0  = cvtpk(yt0[0], yt0[1]);
            P1  = cvtpk(yt0[2], yt0[3]);
            P2c = cvtpk(yt1[0], yt1[1]);
            P3  = cvtpk(yt1[2], yt1[3]);
        }
    }
}

extern "C" void kernel_launch(void* const* d_in, const int* in_sizes, int n_in,
                              void* d_out, int out_size, void* d_ws, size_t ws_size,
                              hipStream_t stream) {
    (void)in_sizes; (void)n_in; (void)d_ws; (void)ws_size; (void)out_size;
    const float* x  = (const float*)d_in[0];
    const float* t  = (const float*)d_in[1];
    // d_in[2] = itv, d_in[3] = itv_mask : unused by the reference math
    const float* W1 = (const float*)d_in[4];
    const float* b1 = (const float*)d_in[5];
    const float* W2 = (const float*)d_in[6];
    const float* b2 = (const float*)d_in[7];
    float* out = (float*)d_out;

    dim3 grid(8192 / 16);   // 512 one-wave blocks: 2 independent waves/CU, 0 barriers
    dim3 block(64);
    hipLaunchKernelGGL(NeuralODE_dopri5_r17, grid, block, 0, stream,
                       x, t, W1, b1, W2, b2, out);
}

// Round 18
// 232.046 us; speedup vs baseline: 1.2091x; 1.2091x over previous
//
#include <hip/hip_runtime.h>

#define TT 65
#define NSTEP 64

typedef __attribute__((ext_vector_type(8))) short bf16x8;
typedef __attribute__((ext_vector_type(4))) float f32x4;
typedef __attribute__((ext_vector_type(4))) unsigned int u32x4;

#define MFMA32(A,B,C) __builtin_amdgcn_mfma_f32_16x16x32_bf16((A),(B),(C),0,0,0)

#if __has_builtin(__builtin_amdgcn_exp2f)
#define EXP2F(x) __builtin_amdgcn_exp2f(x)
#else
#define EXP2F(x) __expf(0.6931471805599453f * (x))
#endif

__device__ constexpr float ATc[6][5] = {
    {0.f, 0.f, 0.f, 0.f, 0.f},
    {0.2f, 0.f, 0.f, 0.f, 0.f},
    {3.f/40.f, 9.f/40.f, 0.f, 0.f, 0.f},
    {44.f/45.f, -56.f/15.f, 32.f/9.f, 0.f, 0.f},
    {19372.f/6561.f, -25360.f/2187.f, 64448.f/6561.f, -212.f/729.f, 0.f},
    {9017.f/3168.f, -355.f/33.f, 46732.f/5247.f, 49.f/176.f, -5103.f/18656.f}
};
__device__ constexpr float BTc[6] = {35.f/384.f, 0.f, 500.f/1113.f, 125.f/192.f,
                                     -2187.f/6784.f, 11.f/84.f};

__device__ __forceinline__ float tanh_fast(float x) {
    // tanh(x) = 1 - 2/(exp(2x)+1); exp(2x) = exp2(x * 2*log2(e))
    float e = EXP2F(x * 2.8853900817779268f);
    return fmaf(-2.0f, __builtin_amdgcn_rcpf(e + 1.0f), 1.0f);
}

// Barrier-lite (R16-proven): LDS producer->consumer needs only lgkmcnt(0);
// __syncthreads would also drain vmcnt(0) and stall on the out-store.
__device__ __forceinline__ void barrier_lds() {
    asm volatile("s_waitcnt lgkmcnt(0)" ::: "memory");
    __builtin_amdgcn_s_barrier();
}

// pack hi16(b):hi16(a) in one v_perm_b32 (weights init only)
__device__ __forceinline__ unsigned int permhi(unsigned int b, unsigned int a) {
    return __builtin_amdgcn_perm(b, a, 0x07060302u);
}
__device__ __forceinline__ unsigned int packpair_init(float a, float b) {
    return permhi(__float_as_uint(b) + 0x8000u, __float_as_uint(a) + 0x8000u);
}
__device__ __forceinline__ bf16x8 pack8(const float* v) {
    u32x4 H = {packpair_init(v[0], v[1]), packpair_init(v[2], v[3]),
               packpair_init(v[4], v[5]), packpair_init(v[6], v[7])};
    return __builtin_bit_cast(bf16x8, H);
}

// hot-path pack via HW v_cvt_pk_bf16_f32 (R16-proven)
__device__ __forceinline__ unsigned int cvtpk(float a, float b) {
    unsigned int r;
    asm("v_cvt_pk_bf16_f32 %0, %1, %2" : "=v"(r) : "v"(a), "v"(b));
    return r;
}
__device__ __forceinline__ bf16x8 packz(f32x4 a, f32x4 b) {
    u32x4 H = {cvtpk(a[0], a[1]), cvtpk(a[2], a[3]),
               cvtpk(b[0], b[1]), cvtpk(b[2], b[3])};
    return __builtin_bit_cast(bf16x8, H);
}

// Block = 4 waves = 16 rows, grid 512 (2 blocks/CU) — R6..R16 geometry, the
// proven optimum across 6 structure experiments. R18 delta vs R16:
//   s_setprio(1) around the compute phase (m1 -> tanh -> pack -> m2 ->
//   partial store). Two blocks/CU slide through different phases; priority
//   lets the compute-phase block preempt the owner/barrier-phase block
//   (the m191 attn regime, not the m190 lockstep-GEMM null).
__global__ __launch_bounds__(256, 2)
void NeuralODE_dopri5_r18(const float* __restrict__ x, const float* __restrict__ tptr,
                          const float* __restrict__ W1, const float* __restrict__ b1,
                          const float* __restrict__ W2, const float* __restrict__ b2,
                          float* __restrict__ out)
{
    __shared__ unsigned int ytp[16][16];             // yt plane (single): 1 KB
    __shared__ __align__(16) float pb[4][512];       // m2 partials: 8 KB

    const int tid = threadIdx.x;
    const int w   = tid >> 6;
    const int l   = tid & 63;
    const int r   = l & 15;
    const int q   = l >> 4;
    const int g   = (r >> 1) & 3;                    // plane block swizzle (R6-proven)
    const int swz = (r & 7) << 2;                    // f32-block swizzle (R4-proven)
    const int row = blockIdx.x * 16 + r;
    const int d0  = 8 * w + 2 * q;                   // owned state pair

    // ---- static weight fragments (single-plane bf16, R15-proven) ----
    bf16x8 W1f[2];
    f32x4 b1f[2];
    {
        float v[8];
        #pragma unroll
        for (int i = 0; i < 2; ++i) {
            int m = 2 * w + i;
            *(f32x4*)&v[0] = *(const f32x4*)&W1[(16*m + r) * 32 + 8*q];
            *(f32x4*)&v[4] = *(const f32x4*)&W1[(16*m + r) * 32 + 8*q + 4];
            W1f[i] = pack8(v);
            b1f[i] = *(const f32x4*)&b1[16*m + 4*q];
        }
    }
    // W2 A-fragments with the sigma K-permutation (R12-proven):
    //   A[r][8q+j] = W2[16dt + r][32w + (j<4 ? 4q+j : 16 + 4q + j-4)]
    bf16x8 W2f[2];
    {
        float v[8];
        #pragma unroll
        for (int dt = 0; dt < 2; ++dt) {
            *(f32x4*)&v[0] = *(const f32x4*)&W2[(16*dt + r) * 128 + 32*w + 4*q];
            *(f32x4*)&v[4] = *(const f32x4*)&W2[(16*dt + r) * 128 + 32*w + 16 + 4*q];
            W2f[dt] = pack8(v);
        }
    }
    // b2 folded into wave-0's m2 accumulator init (C-operand); other waves zero.
    const f32x4 zero = {0.f, 0.f, 0.f, 0.f};
    f32x4 acc_init[2];
    #pragma unroll
    for (int dt = 0; dt < 2; ++dt)
        acc_init[dt] = (w == 0) ? *(const f32x4*)&b2[16*dt + 4*q] : zero;

    // ---- loop-invariant LDS addresses ----
    unsigned int* const ytw = &ytp[r][((w ^ g) << 2) + q];
    const u32x4* const ytr  = (const u32x4*)&ytp[r][(q ^ g) << 2];
    float* const pbw0 = &pb[w][r * 32 + ((     4*q) ^ swz)];
    float* const pbw1 = &pb[w][r * 32 + ((16 + 4*q) ^ swz)];
    const float* const pred = &pb[0][r * 32 + (d0 ^ swz)];   // + 512*v

    const float h_all = tptr[l + 1] - tptr[l];   // t row 0 uniform; lane s has h_s

    // ---- state init ----
    float2 y0 = *(const float2*)&x[(size_t)row * (TT*32) + d0];
    float yx = y0.x, yy = y0.y;
    *ytw = cvtpk(yx, yy);
    *(float2*)&out[(size_t)row * (TT*32) + d0] = y0;
    float kxs[5], kys[5];
    barrier_lds();

    #pragma unroll 1
    for (int step = 0; step < NSTEP; ++step) {
        const float h = __shfl(h_all, step);
        float bax = 0.f, bay = 0.f;

        #pragma unroll
        for (int s = 0; s < 6; ++s) {
            // ======== compute phase: boosted priority ========
            __builtin_amdgcn_s_setprio(1);

            // ---- B1 fragment: single plane, direct from LDS ----
            bf16x8 B1 = __builtin_bit_cast(bf16x8, *ytr);

            // ---- m1: 2 tiles x 1 MFMA + tanh ----
            f32x4 z0 = MFMA32(W1f[0], B1, b1f[0]);
            f32x4 z1 = MFMA32(W1f[1], B1, b1f[1]);
            #pragma unroll
            for (int e = 0; e < 4; ++e) { z0[e] = tanh_fast(z0[e]); z1[e] = tanh_fast(z1[e]); }

            // ---- z -> single-plane MFMA32 B-fragment (sigma concat) ----
            bf16x8 Zh = packz(z0, z1);

            // ---- m2: 2 d-tiles x 1 MFMA, K=32 ----
            f32x4 p0 = MFMA32(W2f[0], Zh, acc_init[0]);
            f32x4 p1 = MFMA32(W2f[1], Zh, acc_init[1]);
            *(f32x4*)pbw0 = p0;
            *(f32x4*)pbw1 = p1;

            __builtin_amdgcn_s_setprio(0);
            barrier_lds();

            // ---- owner: reduce 4 partials (b2 already in), update, publish ----
            float2 pp0 = *(const float2*)&pred[0 * 512];
            float2 pp1 = *(const float2*)&pred[1 * 512];
            float2 pp2 = *(const float2*)&pred[2 * 512];
            float2 pp3 = *(const float2*)&pred[3 * 512];
            float kx = (pp0.x + pp1.x) + (pp2.x + pp3.x);
            float ky = (pp0.y + pp1.y) + (pp2.y + pp3.y);
            if (s < 5) { kxs[s] = kx; kys[s] = ky; }
            bax = fmaf(BTc[s], kx, bax);
            bay = fmaf(BTc[s], ky, bay);

            float ytx, yty;
            if (s < 5) {
                float ax = ATc[s+1][s] * kx;
                float ay = ATc[s+1][s] * ky;
                #pragma unroll
                for (int j = 0; j < 5; ++j)
                    if (j < s) { ax = fmaf(ATc[s+1][j], kxs[j], ax);
                                 ay = fmaf(ATc[s+1][j], kys[j], ay); }
                ytx = fmaf(h, ax, yx);
                yty = fmaf(h, ay, yy);
            } else {
                yx = fmaf(h, bax, yx);
                yy = fmaf(h, bay, yy);
                ytx = yx; yty = yy;
                float2 yn = {yx, yy};
                *(float2*)&out[(size_t)row * (TT*32) + (size_t)(step+1) * 32 + d0] = yn;
            }
            *ytw = cvtpk(ytx, yty);
            barrier_lds();
        }
    }
}

extern "C" void kernel_launch(void* const* d_in, const int* in_sizes, int n_in,
                              void* d_out, int out_size, void* d_ws, size_t ws_size,
                              hipStream_t stream) {
    (void)in_sizes; (void)n_in; (void)d_ws; (void)ws_size; (void)out_size;
    const float* x  = (const float*)d_in[0];
    const float* t  = (const float*)d_in[1];
    // d_in[2] = itv, d_in[3] = itv_mask : unused by the reference math
    const float* W1 = (const float*)d_in[4];
    const float* b1 = (const float*)d_in[5];
    const float* W2 = (const float*)d_in[6];
    const float* b2 = (const float*)d_in[7];
    float* out = (float*)d_out;

    dim3 grid(8192 / 16);   // 512 blocks x 4 waves (2 blocks/CU, R6 geometry)
    dim3 block(256);
    hipLaunchKernelGGL(NeuralODE_dopri5_r18, grid, block, 0, stream,
                       x, t, W1, b1, W2, b2, out);
}

// Round 19
// 219.579 us; speedup vs baseline: 1.2777x; 1.0568x over previous
//
#include <hip/hip_runtime.h>

#define TT 65
#define NSTEP 64

typedef __attribute__((ext_vector_type(8))) short bf16x8;
typedef __attribute__((ext_vector_type(4))) float f32x4;
typedef __attribute__((ext_vector_type(4))) unsigned int u32x4;

#define MFMA32(A,B,C) __builtin_amdgcn_mfma_f32_16x16x32_bf16((A),(B),(C),0,0,0)

// native exp2 (single trans op); fallback keeps correctness if builtin absent
#if __has_builtin(__builtin_amdgcn_exp2f)
#define EXP2F(x) __builtin_amdgcn_exp2f(x)
#else
#define EXP2F(x) __expf(0.6931471805599453f * (x))
#endif

__device__ constexpr float ATc[6][5] = {
    {0.f, 0.f, 0.f, 0.f, 0.f},
    {0.2f, 0.f, 0.f, 0.f, 0.f},
    {3.f/40.f, 9.f/40.f, 0.f, 0.f, 0.f},
    {44.f/45.f, -56.f/15.f, 32.f/9.f, 0.f, 0.f},
    {19372.f/6561.f, -25360.f/2187.f, 64448.f/6561.f, -212.f/729.f, 0.f},
    {9017.f/3168.f, -355.f/33.f, 46732.f/5247.f, 49.f/176.f, -5103.f/18656.f}
};
__device__ constexpr float BTc[6] = {35.f/384.f, 0.f, 500.f/1113.f, 125.f/192.f,
                                     -2187.f/6784.f, 11.f/84.f};

__device__ __forceinline__ float tanh_fast(float x) {
    // tanh(x) = 1 - 2/(exp(2x)+1); exp(2x) = exp2(x * 2*log2(e))
    float e = EXP2F(x * 2.8853900817779268f);
    return fmaf(-2.0f, __builtin_amdgcn_rcpf(e + 1.0f), 1.0f);
}

// Barrier-lite (R16-proven): LDS producer->consumer needs only lgkmcnt(0);
// __syncthreads would also drain vmcnt(0) and stall on the out-store.
__device__ __forceinline__ void barrier_lds() {
    asm volatile("s_waitcnt lgkmcnt(0)" ::: "memory");
    __builtin_amdgcn_s_barrier();
}

// pack hi16(b):hi16(a) in one v_perm_b32 (weights init only)
__device__ __forceinline__ unsigned int permhi(unsigned int b, unsigned int a) {
    return __builtin_amdgcn_perm(b, a, 0x07060302u);
}
__device__ __forceinline__ unsigned int packpair_init(float a, float b) {
    return permhi(__float_as_uint(b) + 0x8000u, __float_as_uint(a) + 0x8000u);
}
__device__ __forceinline__ bf16x8 pack8(const float* v) {
    u32x4 H = {packpair_init(v[0], v[1]), packpair_init(v[2], v[3]),
               packpair_init(v[4], v[5]), packpair_init(v[6], v[7])};
    return __builtin_bit_cast(bf16x8, H);
}

// hot-path pack via HW v_cvt_pk_bf16_f32 (1 VOP3 per pair, RNE) — R16-proven
__device__ __forceinline__ unsigned int cvtpk(float a, float b) {
    unsigned int r;
    asm("v_cvt_pk_bf16_f32 %0, %1, %2" : "=v"(r) : "v"(a), "v"(b));
    return r;
}
__device__ __forceinline__ bf16x8 packz(f32x4 a, f32x4 b) {
    u32x4 H = {cvtpk(a[0], a[1]), cvtpk(a[2], a[3]),
               cvtpk(b[0], b[1]), cvtpk(b[2], b[3])};
    return __builtin_bit_cast(bf16x8, H);
}

// FINAL (== R16, the banked optimum): Block = 4 waves = 16 rows, grid 512
// (2 blocks/CU). Per stage, wave w: B1 (single bf16 yt plane) from LDS ->
// m1 = 2x MFMA32 (single-plane bf16 W1) -> tanh x8 -> cvt_pk z pack ->
// m2 = 2x MFMA32 (sigma K-permutation, z in registers) -> partials ->
// lgkm-barrier -> owner lane reduces 4 partials, Butcher-updates its d-pair,
// publishes next yt plane -> lgkm-barrier. Proven against 7 alternative
// structures (R3,R5,R7,R8,R9,R17,R18); remaining wall is the 384-stage
// serial chain latency, not any hardware pipe.
__global__ __launch_bounds__(256, 2)
void NeuralODE_dopri5_final(const float* __restrict__ x, const float* __restrict__ tptr,
                            const float* __restrict__ W1, const float* __restrict__ b1,
                            const float* __restrict__ W2, const float* __restrict__ b2,
                            float* __restrict__ out)
{
    __shared__ unsigned int ytp[16][16];             // yt plane (single): 1 KB
    __shared__ __align__(16) float pb[4][512];       // m2 partials: 8 KB

    const int tid = threadIdx.x;
    const int w   = tid >> 6;
    const int l   = tid & 63;
    const int r   = l & 15;
    const int q   = l >> 4;
    const int g   = (r >> 1) & 3;                    // plane block swizzle (R6-proven)
    const int swz = (r & 7) << 2;                    // f32-block swizzle (R4-proven)
    const int row = blockIdx.x * 16 + r;
    const int d0  = 8 * w + 2 * q;                   // owned state pair

    // ---- static weight fragments (single-plane bf16, R15-proven) ----
    bf16x8 W1f[2];
    f32x4 b1f[2];
    {
        float v[8];
        #pragma unroll
        for (int i = 0; i < 2; ++i) {
            int m = 2 * w + i;
            *(f32x4*)&v[0] = *(const f32x4*)&W1[(16*m + r) * 32 + 8*q];
            *(f32x4*)&v[4] = *(const f32x4*)&W1[(16*m + r) * 32 + 8*q + 4];
            W1f[i] = pack8(v);
            b1f[i] = *(const f32x4*)&b1[16*m + 4*q];
        }
    }
    // W2 A-fragments with the sigma K-permutation (R12-proven):
    //   A[r][8q+j] = W2[16dt + r][32w + (j<4 ? 4q+j : 16 + 4q + j-4)]
    bf16x8 W2f[2];
    {
        float v[8];
        #pragma unroll
        for (int dt = 0; dt < 2; ++dt) {
            *(f32x4*)&v[0] = *(const f32x4*)&W2[(16*dt + r) * 128 + 32*w + 4*q];
            *(f32x4*)&v[4] = *(const f32x4*)&W2[(16*dt + r) * 128 + 32*w + 16 + 4*q];
            W2f[dt] = pack8(v);
        }
    }
    // b2 folded into wave-0's m2 accumulator init (C-operand); other waves zero.
    const f32x4 zero = {0.f, 0.f, 0.f, 0.f};
    f32x4 acc_init[2];
    #pragma unroll
    for (int dt = 0; dt < 2; ++dt)
        acc_init[dt] = (w == 0) ? *(const f32x4*)&b2[16*dt + 4*q] : zero;

    // ---- loop-invariant LDS addresses ----
    unsigned int* const ytw = &ytp[r][((w ^ g) << 2) + q];
    const u32x4* const ytr  = (const u32x4*)&ytp[r][(q ^ g) << 2];
    float* const pbw0 = &pb[w][r * 32 + ((     4*q) ^ swz)];
    float* const pbw1 = &pb[w][r * 32 + ((16 + 4*q) ^ swz)];
    const float* const pred = &pb[0][r * 32 + (d0 ^ swz)];   // + 512*v

    const float h_all = tptr[l + 1] - tptr[l];   // t row 0 uniform; lane s has h_s

    // ---- state init ----
    float2 y0 = *(const float2*)&x[(size_t)row * (TT*32) + d0];
    float yx = y0.x, yy = y0.y;
    *ytw = cvtpk(yx, yy);
    *(float2*)&out[(size_t)row * (TT*32) + d0] = y0;
    float kxs[5], kys[5];
    barrier_lds();

    #pragma unroll 1
    for (int step = 0; step < NSTEP; ++step) {
        const float h = __shfl(h_all, step);
        float bax = 0.f, bay = 0.f;

        #pragma unroll
        for (int s = 0; s < 6; ++s) {
            // ---- B1 fragment: single plane, direct from LDS ----
            bf16x8 B1 = __builtin_bit_cast(bf16x8, *ytr);

            // ---- m1: 2 tiles x 1 MFMA + tanh ----
            f32x4 z0 = MFMA32(W1f[0], B1, b1f[0]);
            f32x4 z1 = MFMA32(W1f[1], B1, b1f[1]);
            #pragma unroll
            for (int e = 0; e < 4; ++e) { z0[e] = tanh_fast(z0[e]); z1[e] = tanh_fast(z1[e]); }

            // ---- z -> single-plane MFMA32 B-fragment (sigma concat) ----
            bf16x8 Zh = packz(z0, z1);

            // ---- m2: 2 d-tiles x 1 MFMA, K=32 ----
            f32x4 p0 = MFMA32(W2f[0], Zh, acc_init[0]);
            f32x4 p1 = MFMA32(W2f[1], Zh, acc_init[1]);
            *(f32x4*)pbw0 = p0;
            *(f32x4*)pbw1 = p1;
            barrier_lds();

            // ---- owner: reduce 4 partials (b2 already in), update, publish ----
            float2 pp0 = *(const float2*)&pred[0 * 512];
            float2 pp1 = *(const float2*)&pred[1 * 512];
            float2 pp2 = *(const float2*)&pred[2 * 512];
            float2 pp3 = *(const float2*)&pred[3 * 512];
            float kx = (pp0.x + pp1.x) + (pp2.x + pp3.x);
            float ky = (pp0.y + pp1.y) + (pp2.y + pp3.y);
            if (s < 5) { kxs[s] = kx; kys[s] = ky; }
            bax = fmaf(BTc[s], kx, bax);
            bay = fmaf(BTc[s], ky, bay);

            float ytx, yty;
            if (s < 5) {
                float ax = ATc[s+1][s] * kx;
                float ay = ATc[s+1][s] * ky;
                #pragma unroll
                for (int j = 0; j < 5; ++j)
                    if (j < s) { ax = fmaf(ATc[s+1][j], kxs[j], ax);
                                 ay = fmaf(ATc[s+1][j], kys[j], ay); }
                ytx = fmaf(h, ax, yx);
                yty = fmaf(h, ay, yy);
            } else {
                yx = fmaf(h, bax, yx);
                yy = fmaf(h, bay, yy);
                ytx = yx; yty = yy;
                float2 yn = {yx, yy};
                *(float2*)&out[(size_t)row * (TT*32) + (size_t)(step+1) * 32 + d0] = yn;
            }
            *ytw = cvtpk(ytx, yty);
            barrier_lds();
        }
    }
}

extern "C" void kernel_launch(void* const* d_in, const int* in_sizes, int n_in,
                              void* d_out, int out_size, void* d_ws, size_t ws_size,
                              hipStream_t stream) {
    (void)in_sizes; (void)n_in; (void)d_ws; (void)ws_size; (void)out_size;
    const float* x  = (const float*)d_in[0];
    const float* t  = (const float*)d_in[1];
    // d_in[2] = itv, d_in[3] = itv_mask : unused by the reference math
    const float* W1 = (const float*)d_in[4];
    const float* b1 = (const float*)d_in[5];
    const float* W2 = (const float*)d_in[6];
    const float* b2 = (const float*)d_in[7];
    float* out = (float*)d_out;

    dim3 grid(8192 / 16);   // 512 blocks x 4 waves (2 blocks/CU, R6 geometry)
    dim3 block(256);
    hipLaunchKernelGGL(NeuralODE_dopri5_final, grid, block, 0, stream,
                       x, t, W1, b1, W2, b2, out);
}